// Round 9
// baseline (657.894 us; speedup 1.0000x reference)
//
#include <hip/hip_runtime.h>
#include <hip/hip_bf16.h>
#include <cstdint>

using bf16x8 = __attribute__((ext_vector_type(8))) short;
using f32x4  = __attribute__((ext_vector_type(4))) float;
using bf16_t = __hip_bfloat16;

#define DEVI static __device__ __forceinline__

constexpr int kB = 4, kC = 256, kNH = 8, kDh = 32;
constexpr int kVP = 6, kVW = 16, kHP = 32, kHW = 3;
constexpr int kNW = 48, kP = 192, kGRID = 96;
constexpr int kRows = kB * kNW * kP;    // 36864
constexpr int kFF = 1024;
constexpr float kScale = 0.0625f;       // 1/sqrt(C)

// row -> (b, g1, g2): window (vw,hw), patch (vp,hp); rolled grid coords
DEVI void row_coords(int row, int& b, int& g1, int& g2) {
  int b_  = row / (kNW * kP);
  int rem = row - b_ * (kNW * kP);
  int w = rem / kP;
  int p = rem - w * kP;
  int vw = w / kHW, hw = w - vw * kHW;
  int vp = p >> 5,  hp = p & 31;
  int r  = vp * kVW + vw;
  int cc = hp * kHW + hw;
  g1 = r + 80;  if (g1 >= kGRID) g1 -= kGRID;
  g2 = cc + 93; if (g2 >= kGRID) g2 -= kGRID;
  b = b_;
}

DEVI float bf2f(short s) {
  union { unsigned u; float f; } c;
  c.u = ((unsigned)(unsigned short)s) << 16;
  return c.f;
}
DEVI short f2bf(float f) {
  bf16_t h = __float2bfloat16(f);
  return *reinterpret_cast<short*>(&h);
}

DEVI void gload16(const void* g, void* l) {
  __builtin_amdgcn_global_load_lds(
      (__attribute__((address_space(1))) void*)(uintptr_t)g,
      (__attribute__((address_space(3))) void*)(uintptr_t)l, 16, 0, 0);
}

template <int N> DEVI void wait_vm() {
  if constexpr (N == 0)      asm volatile("s_waitcnt vmcnt(0)" ::: "memory");
  else if constexpr (N == 2) asm volatile("s_waitcnt vmcnt(2)" ::: "memory");
  else if constexpr (N == 4) asm volatile("s_waitcnt vmcnt(4)" ::: "memory");
  else if constexpr (N == 6) asm volatile("s_waitcnt vmcnt(6)" ::: "memory");
  else if constexpr (N == 8) asm volatile("s_waitcnt vmcnt(8)" ::: "memory");
  __builtin_amdgcn_sched_barrier(0);
}
DEVI void barrier_fence() {
  __builtin_amdgcn_s_barrier();
  __builtin_amdgcn_sched_barrier(0);
}

DEVI float gelu_fast(float v) {
  // tanh-form GELU via expf; clamped so e stays finite. |err| < ~3e-4.
  const float t = v * 0.7978845608f * (1.f + 0.044715f * v * v);
  const float e = __expf(fminf(-2.f * t, 60.f));
  return 0.5f * v * (1.f + (1.f - e) / (1.f + e));
}

// ---------------- weight convert
__global__ __launch_bounds__(256) void k_wconv(
    const float* __restrict__ wq, const float* __restrict__ wk,
    const float* __restrict__ wv, const float* __restrict__ w1,
    const float* __restrict__ w2, bf16_t* __restrict__ W) {
  const int i = blockIdx.x * 256 + threadIdx.x;
  if (i < 196608) {                       // WqkvT: n*256+k
    const int n = i >> 8, k = i & 255;
    const float* src = n < 256 ? wq : (n < 512 ? wk : wv);
    W[i] = __float2bfloat16(src[k * 256 + (n & 255)]);
  } else if (i < 458752) {                // W1T: n*256+k, n<1024
    const int j = i - 196608;
    const int n = j >> 8, k = j & 255;
    W[i] = __float2bfloat16(w1[k * 1024 + n]);
  } else if (i < 720896) {                // W2T: n*1024+k, n<256
    const int j = i - 458752;
    const int n = j >> 10, k = j & 1023;
    W[i] = __float2bfloat16(w2[k * 256 + n]);
  }
}

// ---------------- gather + LN1 -> Y bf16
__global__ __launch_bounds__(256) void k_ln1(const float* __restrict__ emb,
    const float* __restrict__ gam, const float* __restrict__ bet,
    bf16_t* __restrict__ Y) {
  const int wave = threadIdx.x >> 6, lane = threadIdx.x & 63;
  #pragma unroll
  for (int rr = 0; rr < 2; ++rr) {
    const int row = blockIdx.x * 8 + wave * 2 + rr;
    int b, g1, g2; row_coords(row, b, g1, g2);
    const float* src = emb + (((size_t)b * kGRID + g1) * kGRID + g2) * kC;
    float4 x = *reinterpret_cast<const float4*>(src + lane * 4);
    float s  = x.x + x.y + x.z + x.w;
    float sq = x.x*x.x + x.y*x.y + x.z*x.z + x.w*x.w;
    #pragma unroll
    for (int off = 32; off; off >>= 1) { s += __shfl_xor(s, off); sq += __shfl_xor(sq, off); }
    const float mean = s * (1.f / kC);
    const float rstd = rsqrtf(sq * (1.f / kC) - mean * mean + 1e-5f);
    const float4 g4 = *reinterpret_cast<const float4*>(gam + lane * 4);
    const float4 b4 = *reinterpret_cast<const float4*>(bet + lane * 4);
    short4 o;
    o.x = f2bf((x.x - mean) * rstd * g4.x + b4.x);
    o.y = f2bf((x.y - mean) * rstd * g4.y + b4.y);
    o.z = f2bf((x.z - mean) * rstd * g4.z + b4.z);
    o.w = f2bf((x.w - mean) * rstd * g4.w + b4.w);
    *reinterpret_cast<short4*>(Y + (size_t)row * kC + lane * 4) = o;
  }
}

// ---------------- re-gather + residual + LN2 -> A fp32, H bf16
__global__ __launch_bounds__(256) void k_ln2(const float* __restrict__ emb,
    const bf16_t* __restrict__ SA,
    const float* __restrict__ gam, const float* __restrict__ bet,
    float* __restrict__ A, bf16_t* __restrict__ H) {
  const int wave = threadIdx.x >> 6, lane = threadIdx.x & 63;
  #pragma unroll
  for (int rr = 0; rr < 2; ++rr) {
    const int row = blockIdx.x * 8 + wave * 2 + rr;
    int b, g1, g2; row_coords(row, b, g1, g2);
    const float* src = emb + (((size_t)b * kGRID + g1) * kGRID + g2) * kC;
    float4 x = *reinterpret_cast<const float4*>(src + lane * 4);
    short4 sv = *reinterpret_cast<const short4*>(SA + (size_t)row * kC + lane * 4);
    x.x += bf2f(sv.x); x.y += bf2f(sv.y); x.z += bf2f(sv.z); x.w += bf2f(sv.w);
    *reinterpret_cast<float4*>(A + (size_t)row * kC + lane * 4) = x;
    float s  = x.x + x.y + x.z + x.w;
    float sq = x.x*x.x + x.y*x.y + x.z*x.z + x.w*x.w;
    #pragma unroll
    for (int off = 32; off; off >>= 1) { s += __shfl_xor(s, off); sq += __shfl_xor(sq, off); }
    const float mean = s * (1.f / kC);
    const float rstd = rsqrtf(sq * (1.f / kC) - mean * mean + 1e-5f);
    const float4 g4 = *reinterpret_cast<const float4*>(gam + lane * 4);
    const float4 b4 = *reinterpret_cast<const float4*>(bet + lane * 4);
    short4 o;
    o.x = f2bf((x.x - mean) * rstd * g4.x + b4.x);
    o.y = f2bf((x.y - mean) * rstd * g4.y + b4.y);
    o.z = f2bf((x.z - mean) * rstd * g4.z + b4.z);
    o.w = f2bf((x.w - mean) * rstd * g4.w + b4.w);
    *reinterpret_cast<short4*>(H + (size_t)row * kC + lane * 4) = o;
  }
}

// ---------------- k_gemm5: small-K (K=256) GEMM with B-panel RESIDENT in LDS
// and TM m-tiles per block in one continuous counted-vmcnt pipeline.
// 128x128 output tile, 4 waves (2x2), wave 64x64 (4x4 frags), BK=32.
// B resident [128][256] bf16 (64 KB) XOR-swizzled 16B slots (s^=(r&7)):
// staged coalesced once per block, conflict-free ds_read_b128.
// A double-buffered [128][32] (8 KB each) XOR s^=(r&3).
// Per step: stage A(s+1) (2 gloads/wave) -> vmcnt(2) -> barrier -> 16 MFMA
// -> barrier. Tile epilogue runs BETWEEN steps, overlapping next tile's loads.
// R8 bug fixed here: B chunk = 2 rows x 256 = 512 ELEMENTS -> dest c*512
// (was c*1024: OOB LDS writes + half of Bres never written -> NaN).
template <int EPI, int GX, int TM>
__global__ __launch_bounds__(256, 2) void k_gemm5(
    const bf16_t* __restrict__ Amat, const bf16_t* __restrict__ BT,
    const float* __restrict__ bias0, const float* __restrict__ bias1,
    const float* __restrict__ bias2,
    bf16_t* __restrict__ Obf) {
  constexpr int KDIM = 256;
  __shared__ bf16_t Bres[128 * 256];     // 64 KB resident B panel
  __shared__ bf16_t As[2][128 * 32];     // 8 KB x2 streamed A
  const int tid = threadIdx.x;
  const int wave = tid >> 6, lane = tid & 63;
  const int lr = lane & 15, kg4 = lane >> 4;         // 0..3
  constexpr int MRUNS = (kRows / 128) / TM;          // 72
  constexpr int nwg = MRUNS * GX;
  const int wg = (blockIdx.x & 7) * (nwg >> 3) + (blockIdx.x >> 3);
  const int mrun = wg / GX, ncol = wg % GX;
  const int n0 = ncol * 128;
  const int m0base = mrun * TM * 128;
  const int wm = (wave >> 1) * 64, wn = (wave & 1) * 64;

  // ---- stage B resident (once): 64 chunks of 2 rows (512 elems = 1024 B),
  // coalesced; source 16B-slot pre-swizzled by (row&7).
  {
    const int rl = lane >> 5;                        // 0/1 row within chunk
    #pragma unroll
    for (int i = 0; i < 16; ++i) {
      const int c = wave * 16 + i;                   // 0..63
      const int row = c * 2 + rl;
      const int slot = (lane & 31) ^ (row & 7);
      gload16(BT + (size_t)(n0 + row) * KDIM + slot * 8, &Bres[c * 512]);
    }
  }

  // ---- A staging: tile tt, K-step kk; chunk = 16 rows x 32 cols (1 KB).
  const int arow_l = lane >> 2;                      // 0..15 within chunk
  auto stageA = [&](int sbuf, int tt, int kk) {
    const int m0 = m0base + tt * 128;
    #pragma unroll
    for (int i = 0; i < 2; ++i) {
      const int c = wave * 2 + i;                    // 0..7
      const int row = c * 16 + arow_l;
      const int slot = (lane & 3) ^ (row & 3);
      gload16(Amat + (size_t)(m0 + row) * KDIM + kk * 32 + slot * 8,
              &As[sbuf][c * 512]);
    }
  };

  f32x4 acc[4][4] = {};
  auto computeStep = [&](int cbuf, int k) {
    bf16x8 af[4], bq[4];
    #pragma unroll
    for (int m = 0; m < 4; ++m) {
      const int r = wm + m * 16 + lr;
      af[m] = *reinterpret_cast<const bf16x8*>(
          &As[cbuf][r * 32 + ((kg4 ^ (r & 3)) << 3)]);
    }
    const int kgg = k * 4 + kg4;                     // 0..31 16B k-slot
    #pragma unroll
    for (int n = 0; n < 4; ++n) {
      const int r = wn + n * 16 + lr;
      bq[n] = *reinterpret_cast<const bf16x8*>(
          &Bres[r * 256 + ((kgg ^ (r & 7)) << 3)]);
    }
    __builtin_amdgcn_s_setprio(1);
    #pragma unroll
    for (int m = 0; m < 4; ++m)
      #pragma unroll
      for (int n = 0; n < 4; ++n)
        acc[m][n] = __builtin_amdgcn_mfma_f32_16x16x32_bf16(af[m], bq[n], acc[m][n], 0, 0, 0);
    __builtin_amdgcn_s_setprio(0);
  };

  auto epilogue = [&](int tt) {
    const int m0 = m0base + tt * 128;
    #pragma unroll
    for (int m = 0; m < 4; ++m) {
      #pragma unroll
      for (int n = 0; n < 4; ++n) {
        #pragma unroll
        for (int r = 0; r < 4; ++r) {
          const int row = m0 + wm + m * 16 + kg4 * 4 + r;
          const int col = n0 + wn + n * 16 + lr;
          float v = acc[m][n][r];
          acc[m][n][r] = 0.f;
          if constexpr (EPI == 0) {
            const int which = col >> 8, c = col & 255;
            const float* bp = which == 0 ? bias0 : (which == 1 ? bias1 : bias2);
            v += bp[c];
            Obf[(size_t)which * kRows * kC + (size_t)row * kC + c] = __float2bfloat16(v);
          } else {
            v += bias0[col];
            Obf[(size_t)row * kFF + col] = __float2bfloat16(gelu_fast(v));
          }
        }
      }
    }
  };

  stageA(0, 0, 0);                                   // A(s=0)
  constexpr int S = TM * 8;
  int s = 0;
  #pragma unroll 1
  for (int t = 0; t < TM; ++t) {
    #pragma unroll
    for (int k = 0; k < 8; ++k, ++s) {
      if (s + 1 < S) {
        stageA((s + 1) & 1, (k == 7) ? t + 1 : t, (k + 1) & 7);
        wait_vm<2>();                                // own older loads done
      } else {
        wait_vm<0>();
      }
      barrier_fence();
      computeStep(s & 1, k);
      barrier_fence();
    }
    epilogue(t);                                     // overlaps next tile loads
  }
}

// ---------------- k_gemm4 (R7): counted-vmcnt dbuf GEMM — used for FFN2
// (K=1024: 16-step pipeline). 128x128, 8 waves (2x4), wave 64x32.
template <int KDIM, int EPI, int BM, int BN, int GX>
__global__ __launch_bounds__(512, (BM == 128) ? 4 : 2) void k_gemm4(
    const bf16_t* __restrict__ Amat, const bf16_t* __restrict__ BT,
    const float* __restrict__ bias0, const float* __restrict__ Ares,
    float* __restrict__ Out) {
  constexpr int FM = BM / 32;
  constexpr int FN = BN / 64;
  constexpr int CA = BM / 64;
  constexpr int CB = BN / 64;
  constexpr int L  = CA + CB;
  constexpr int NT = KDIM / 64;
  __shared__ bf16_t As[2][BM * 64];
  __shared__ bf16_t Bs[2][BN * 64];
  const int tid = threadIdx.x;
  const int wave = tid >> 6, lane = tid & 63;
  const int lr = lane & 15, kgf = lane >> 4;
  const int nwg = (kRows / BM) * GX;
  const int wg = (blockIdx.x & 7) * (nwg >> 3) + (blockIdx.x >> 3);
  const int m0 = (wg / GX) * BM, n0 = (wg % GX) * BN;
  const int wm = (wave >> 2) * (BM / 2), wn = (wave & 3) * (BN / 4);
  const int srow = lane >> 3;
  const int scol = ((lane & 7) ^ srow) << 3;

  auto stage = [&](int sbuf, int k0) {
    #pragma unroll
    for (int i = 0; i < CA; ++i) {
      const int c = wave * CA + i;
      gload16(Amat + (size_t)(m0 + c * 8 + srow) * KDIM + k0 + scol,
              &As[sbuf][c * 512]);
    }
    #pragma unroll
    for (int i = 0; i < CB; ++i) {
      const int c = wave * CB + i;
      gload16(BT + (size_t)(n0 + c * 8 + srow) * KDIM + k0 + scol,
              &Bs[sbuf][c * 512]);
    }
  };

  f32x4 acc[FM][FN] = {};
  auto compute = [&](int cbuf) {
    #pragma unroll
    for (int kk = 0; kk < 2; ++kk) {
      const int kgg = kk * 4 + kgf;
      bf16x8 af[FM], bq[FN];
      #pragma unroll
      for (int m = 0; m < FM; ++m) {
        const int r = wm + m * 16 + lr;
        af[m] = *reinterpret_cast<const bf16x8*>(&As[cbuf][r * 64 + ((kgg ^ (r & 7)) << 3)]);
      }
      #pragma unroll
      for (int n = 0; n < FN; ++n) {
        const int r = wn + n * 16 + lr;
        bq[n] = *reinterpret_cast<const bf16x8*>(&Bs[cbuf][r * 64 + ((kgg ^ (r & 7)) << 3)]);
      }
      __builtin_amdgcn_s_setprio(1);
      #pragma unroll
      for (int m = 0; m < FM; ++m)
        #pragma unroll
        for (int n = 0; n < FN; ++n)
          acc[m][n] = __builtin_amdgcn_mfma_f32_16x16x32_bf16(af[m], bq[n], acc[m][n], 0, 0, 0);
      __builtin_amdgcn_s_setprio(0);
    }
  };

  stage(0, 0);
  #pragma unroll
  for (int t = 0; t < NT; ++t) {
    const int buf = t & 1;
    if (t + 1 < NT) {
      stage(buf ^ 1, (t + 1) * 64);
      wait_vm<L>();
    } else {
      wait_vm<0>();
    }
    barrier_fence();
    compute(buf);
    barrier_fence();
  }

  #pragma unroll
  for (int m = 0; m < FM; ++m) {
    #pragma unroll
    for (int n = 0; n < FN; ++n) {
      #pragma unroll
      for (int r = 0; r < 4; ++r) {
        const int row = m0 + wm + m * 16 + kgf * 4 + r;
        const int col = n0 + wn + n * 16 + lr;
        float v = acc[m][n][r] + bias0[col] + Ares[(size_t)row * kC + col];
        int b, g1, g2; row_coords(row, b, g1, g2);
        Out[(((size_t)b * kGRID + g1) * kGRID + g2) * kC + col] = v;
      }
    }
  }
}

// ---------------- MFMA attention (unchanged)
constexpr int kKsPad = 40;
constexpr int kVtPad = 200;
constexpr int kPlPad = 200;
__global__ __launch_bounds__(256) void k_attn(
    const bf16_t* __restrict__ Q, const bf16_t* __restrict__ K,
    const bf16_t* __restrict__ V, const float* __restrict__ pos,
    bf16_t* __restrict__ SA) {
  __shared__ short Ks[kP * kKsPad];
  __shared__ short Vt[kDh * kVtPad];
  __shared__ short Pl[4 * 16 * kPlPad];
  const int bw = blockIdx.x >> 3, h = blockIdx.x & 7;
  const int rowbase = bw * kP, colbase = h * kDh;
  const int tid = threadIdx.x, wave = tid >> 6, lane = tid & 63;
  const int lr = lane & 15, kg = lane >> 4;
  const int wq0 = wave * 48;
  const float* pb = pos + (size_t)h * kP * kP;

  #pragma unroll
  for (int i = 0; i < 3; ++i) {
    const int c = tid + i * 256;
    const int row = c >> 2, dch = (c & 3) * 8;
    const size_t gbase = (size_t)(rowbase + row) * kC + colbase + dch;
    bf16x8 kv = *reinterpret_cast<const bf16x8*>(K + gbase);
    *reinterpret_cast<bf16x8*>(&Ks[row * kKsPad + dch]) = kv;
    bf16x8 vv = *reinterpret_cast<const bf16x8*>(V + gbase);
    #pragma unroll
    for (int e = 0; e < 8; ++e) Vt[(dch + e) * kVtPad + row] = vv[e];
  }
  __syncthreads();

  for (int m = 0; m < 3; ++m) {
    const int rbase = wq0 + m * 16;
    bf16x8 aq = *reinterpret_cast<const bf16x8*>(
        Q + (size_t)(rowbase + rbase + lr) * kC + colbase + kg * 8);
    f32x4 s[12];
    #pragma unroll
    for (int n = 0; n < 12; ++n) {
      bf16x8 bk = *reinterpret_cast<const bf16x8*>(&Ks[(n * 16 + lr) * kKsPad + kg * 8]);
      s[n] = __builtin_amdgcn_mfma_f32_16x16x32_bf16(aq, bk, (f32x4){0.f, 0.f, 0.f, 0.f}, 0, 0, 0);
    }
    float mx[4] = {-1e30f, -1e30f, -1e30f, -1e30f};
    #pragma unroll
    for (int n = 0; n < 12; ++n) {
      #pragma unroll
      for (int r = 0; r < 4; ++r) {
        const float lg = fmaf(s[n][r], kScale,
                              pb[(size_t)(rbase + kg * 4 + r) * kP + n * 16 + lr]);
        s[n][r] = lg;
        mx[r] = fmaxf(mx[r], lg);
      }
    }
    #pragma unroll
    for (int r = 0; r < 4; ++r)
      #pragma unroll
      for (int off = 8; off; off >>= 1) mx[r] = fmaxf(mx[r], __shfl_xor(mx[r], off));
    float sm[4] = {0.f, 0.f, 0.f, 0.f};
    #pragma unroll
    for (int n = 0; n < 12; ++n)
      #pragma unroll
      for (int r = 0; r < 4; ++r) {
        const float e = __expf(s[n][r] - mx[r]);
        s[n][r] = e;
        sm[r] += e;
      }
    #pragma unroll
    for (int r = 0; r < 4; ++r) {
      #pragma unroll
      for (int off = 8; off; off >>= 1) sm[r] += __shfl_xor(sm[r], off);
      sm[r] = 1.f / sm[r];
    }
    #pragma unroll
    for (int n = 0; n < 12; ++n)
      #pragma unroll
      for (int r = 0; r < 4; ++r)
        Pl[(wave * 16 + kg * 4 + r) * kPlPad + n * 16 + lr] = f2bf(s[n][r] * sm[r]);
    f32x4 o0 = {0.f, 0.f, 0.f, 0.f}, o1 = {0.f, 0.f, 0.f, 0.f};
    #pragma unroll
    for (int kk = 0; kk < 6; ++kk) {
      bf16x8 ap = *reinterpret_cast<const bf16x8*>(&Pl[(wave * 16 + lr) * kPlPad + kk * 32 + kg * 8]);
      bf16x8 b0 = *reinterpret_cast<const bf16x8*>(&Vt[lr * kVtPad + kk * 32 + kg * 8]);
      bf16x8 b1 = *reinterpret_cast<const bf16x8*>(&Vt[(16 + lr) * kVtPad + kk * 32 + kg * 8]);
      o0 = __builtin_amdgcn_mfma_f32_16x16x32_bf16(ap, b0, o0, 0, 0, 0);
      o1 = __builtin_amdgcn_mfma_f32_16x16x32_bf16(ap, b1, o1, 0, 0, 0);
    }
    bf16_t* sp = SA + (size_t)(rowbase + rbase + kg * 4) * kC + colbase;
    #pragma unroll
    for (int r = 0; r < 4; ++r) {
      sp[(size_t)r * kC + lr]      = __float2bfloat16(o0[r]);
      sp[(size_t)r * kC + 16 + lr] = __float2bfloat16(o1[r]);
    }
  }
}

extern "C" void kernel_launch(void* const* d_in, const int* in_sizes, int n_in,
                              void* d_out, int out_size, void* d_ws, size_t ws_size,
                              hipStream_t stream) {
  const float* emb  = (const float*)d_in[0];
  const float* ln1g = (const float*)d_in[1];
  const float* ln1b = (const float*)d_in[2];
  const float* wq   = (const float*)d_in[3];
  const float* bq   = (const float*)d_in[4];
  const float* wk   = (const float*)d_in[5];
  const float* bk   = (const float*)d_in[6];
  const float* wv   = (const float*)d_in[7];
  const float* bv   = (const float*)d_in[8];
  const float* pos  = (const float*)d_in[9];
  const float* ln2g = (const float*)d_in[10];
  const float* ln2b = (const float*)d_in[11];
  const float* w1   = (const float*)d_in[12];
  const float* b1   = (const float*)d_in[13];
  const float* w2   = (const float*)d_in[14];
  const float* b2   = (const float*)d_in[15];

  char* ws = (char*)d_ws;
  const size_t nYb = (size_t)kRows * kC * 2;               // 18,874,368 B
  bf16_t* Y    = (bf16_t*)(ws);                            // [0, 18.9M)
  bf16_t* Qb   = (bf16_t*)(ws + nYb);                      // Q,K,V consecutive
  bf16_t* SAb  = (bf16_t*)(ws + nYb * 4);                  // [75.5M, 94.4M)
  float*  Abuf = (float*) (ws + nYb * 5);                  // [94.4M, 132.1M)
  bf16_t* H    = (bf16_t*)(ws + nYb * 5 + (size_t)kRows * kC * 4);  // [132.1M, 151M)
  bf16_t* G    = (bf16_t*)(ws);                            // alias dead Y/Q/K/V
  bf16_t* W    = (bf16_t*)(ws + nYb * 5 + (size_t)kRows * kC * 4 + nYb);
  bf16_t* WqkvT = W;
  bf16_t* W1T   = W + 768 * 256;
  bf16_t* W2T   = W1T + 1024 * 256;

  k_wconv<<<2816, 256, 0, stream>>>(wq, wk, wv, w1, w2, W);
  k_ln1<<<kRows / 8, 256, 0, stream>>>(emb, ln1g, ln1b, Y);
  k_gemm5<0, 6, 4><<<72 * 6, 256, 0, stream>>>(
      Y, WqkvT, bq, bk, bv, Qb);
  k_attn<<<kB * kNW * kNH, 256, 0, stream>>>(
      Qb, Qb + (size_t)kRows * kC, Qb + 2 * (size_t)kRows * kC, pos, SAb);
  k_ln2<<<kRows / 8, 256, 0, stream>>>(emb, SAb, ln2g, ln2b, Abuf, H);
  k_gemm5<1, 8, 4><<<72 * 8, 256, 0, stream>>>(
      H, W1T, b1, nullptr, nullptr, G);
  k_gemm4<1024, 2, 128, 128, 2><<<(kRows / 128) * 2, 512, 0, stream>>>(
      G, W2T, b2, Abuf, (float*)d_out);
}

// Round 10
// 193.163 us; speedup vs baseline: 3.4059x; 3.4059x over previous
//
#include <hip/hip_runtime.h>
#include <hip/hip_bf16.h>
#include <cstdint>

using bf16x8 = __attribute__((ext_vector_type(8))) short;
using f32x4  = __attribute__((ext_vector_type(4))) float;
using bf16_t = __hip_bfloat16;

#define DEVI static __device__ __forceinline__

constexpr int kB = 4, kC = 256, kNH = 8, kDh = 32;
constexpr int kVP = 6, kVW = 16, kHP = 32, kHW = 3;
constexpr int kNW = 48, kP = 192, kGRID = 96;
constexpr int kRows = kB * kNW * kP;    // 36864
constexpr int kFF = 1024;
constexpr float kScale = 0.0625f;       // 1/sqrt(C)

// row -> (b, g1, g2): window (vw,hw), patch (vp,hp); rolled grid coords
DEVI void row_coords(int row, int& b, int& g1, int& g2) {
  int b_  = row / (kNW * kP);
  int rem = row - b_ * (kNW * kP);
  int w = rem / kP;
  int p = rem - w * kP;
  int vw = w / kHW, hw = w - vw * kHW;
  int vp = p >> 5,  hp = p & 31;
  int r  = vp * kVW + vw;
  int cc = hp * kHW + hw;
  g1 = r + 80;  if (g1 >= kGRID) g1 -= kGRID;
  g2 = cc + 93; if (g2 >= kGRID) g2 -= kGRID;
  b = b_;
}

DEVI float bf2f(short s) {
  union { unsigned u; float f; } c;
  c.u = ((unsigned)(unsigned short)s) << 16;
  return c.f;
}
DEVI short f2bf(float f) {
  bf16_t h = __float2bfloat16(f);
  return *reinterpret_cast<short*>(&h);
}

DEVI void gload16(const void* g, void* l) {
  __builtin_amdgcn_global_load_lds(
      (__attribute__((address_space(1))) void*)(uintptr_t)g,
      (__attribute__((address_space(3))) void*)(uintptr_t)l, 16, 0, 0);
}

DEVI float gelu_fast(float v) {
  // tanh-form GELU via expf; clamped so e stays finite. |err| < ~3e-4.
  // Validated in R9: pipeline absmax unchanged (0.03125).
  const float t = v * 0.7978845608f * (1.f + 0.044715f * v * v);
  const float e = __expf(fminf(-2.f * t, 60.f));
  return 0.5f * v * (1.f + (1.f - e) / (1.f + e));
}

// ---------------- weight convert
__global__ __launch_bounds__(256) void k_wconv(
    const float* __restrict__ wq, const float* __restrict__ wk,
    const float* __restrict__ wv, const float* __restrict__ w1,
    const float* __restrict__ w2, bf16_t* __restrict__ W) {
  const int i = blockIdx.x * 256 + threadIdx.x;
  if (i < 196608) {                       // WqkvT: n*256+k
    const int n = i >> 8, k = i & 255;
    const float* src = n < 256 ? wq : (n < 512 ? wk : wv);
    W[i] = __float2bfloat16(src[k * 256 + (n & 255)]);
  } else if (i < 458752) {                // W1T: n*256+k, n<1024
    const int j = i - 196608;
    const int n = j >> 8, k = j & 255;
    W[i] = __float2bfloat16(w1[k * 1024 + n]);
  } else if (i < 720896) {                // W2T: n*1024+k, n<256
    const int j = i - 458752;
    const int n = j >> 10, k = j & 1023;
    W[i] = __float2bfloat16(w2[k * 256 + n]);
  }
}

// ---------------- gather + LN1 -> Y bf16
__global__ __launch_bounds__(256) void k_ln1(const float* __restrict__ emb,
    const float* __restrict__ gam, const float* __restrict__ bet,
    bf16_t* __restrict__ Y) {
  const int wave = threadIdx.x >> 6, lane = threadIdx.x & 63;
  #pragma unroll
  for (int rr = 0; rr < 2; ++rr) {
    const int row = blockIdx.x * 8 + wave * 2 + rr;
    int b, g1, g2; row_coords(row, b, g1, g2);
    const float* src = emb + (((size_t)b * kGRID + g1) * kGRID + g2) * kC;
    float4 x = *reinterpret_cast<const float4*>(src + lane * 4);
    float s  = x.x + x.y + x.z + x.w;
    float sq = x.x*x.x + x.y*x.y + x.z*x.z + x.w*x.w;
    #pragma unroll
    for (int off = 32; off; off >>= 1) { s += __shfl_xor(s, off); sq += __shfl_xor(sq, off); }
    const float mean = s * (1.f / kC);
    const float rstd = rsqrtf(sq * (1.f / kC) - mean * mean + 1e-5f);
    const float4 g4 = *reinterpret_cast<const float4*>(gam + lane * 4);
    const float4 b4 = *reinterpret_cast<const float4*>(bet + lane * 4);
    short4 o;
    o.x = f2bf((x.x - mean) * rstd * g4.x + b4.x);
    o.y = f2bf((x.y - mean) * rstd * g4.y + b4.y);
    o.z = f2bf((x.z - mean) * rstd * g4.z + b4.z);
    o.w = f2bf((x.w - mean) * rstd * g4.w + b4.w);
    *reinterpret_cast<short4*>(Y + (size_t)row * kC + lane * 4) = o;
  }
}

// ---------------- re-gather + residual + LN2 -> A fp32, H bf16
__global__ __launch_bounds__(256) void k_ln2(const float* __restrict__ emb,
    const bf16_t* __restrict__ SA,
    const float* __restrict__ gam, const float* __restrict__ bet,
    float* __restrict__ A, bf16_t* __restrict__ H) {
  const int wave = threadIdx.x >> 6, lane = threadIdx.x & 63;
  #pragma unroll
  for (int rr = 0; rr < 2; ++rr) {
    const int row = blockIdx.x * 8 + wave * 2 + rr;
    int b, g1, g2; row_coords(row, b, g1, g2);
    const float* src = emb + (((size_t)b * kGRID + g1) * kGRID + g2) * kC;
    float4 x = *reinterpret_cast<const float4*>(src + lane * 4);
    short4 sv = *reinterpret_cast<const short4*>(SA + (size_t)row * kC + lane * 4);
    x.x += bf2f(sv.x); x.y += bf2f(sv.y); x.z += bf2f(sv.z); x.w += bf2f(sv.w);
    *reinterpret_cast<float4*>(A + (size_t)row * kC + lane * 4) = x;
    float s  = x.x + x.y + x.z + x.w;
    float sq = x.x*x.x + x.y*x.y + x.z*x.z + x.w*x.w;
    #pragma unroll
    for (int off = 32; off; off >>= 1) { s += __shfl_xor(s, off); sq += __shfl_xor(sq, off); }
    const float mean = s * (1.f / kC);
    const float rstd = rsqrtf(sq * (1.f / kC) - mean * mean + 1e-5f);
    const float4 g4 = *reinterpret_cast<const float4*>(gam + lane * 4);
    const float4 b4 = *reinterpret_cast<const float4*>(bet + lane * 4);
    short4 o;
    o.x = f2bf((x.x - mean) * rstd * g4.x + b4.x);
    o.y = f2bf((x.y - mean) * rstd * g4.y + b4.y);
    o.z = f2bf((x.z - mean) * rstd * g4.z + b4.z);
    o.w = f2bf((x.w - mean) * rstd * g4.w + b4.w);
    *reinterpret_cast<short4*>(H + (size_t)row * kC + lane * 4) = o;
  }
}

// ---------------- MFMA GEMM (R6 structure, occupancy-tuned): 128x128 tile,
// BK=32 double-buffered (LDS 32 KB total), 4 waves (2x2), wave 64x64.
// __launch_bounds__(256,4): 4 blocks/CU resident -> cross-block TLP covers
// each block's per-step stage->barrier drain (the R2/R6 86us invariant was
// latency-stall-bound at ~2 blocks/CU: MfmaUtil 8.7 + VALU 23 + 68% idle).
// Staging: chunk = 16 rows x 32 cols, 4 lanes/row, 16B-slot XOR swizzle
// s^=(row&3) applied on BOTH global source and ds_read (rule #21).
// Grid 1D n-fast + XCD-chunked bijective swizzle (T1).
template <int KDIM, int EPI, int GX>
__global__ __launch_bounds__(256, 4) void k_gemm3(
    const bf16_t* __restrict__ Amat, const bf16_t* __restrict__ BT,
    const float* __restrict__ bias0, const float* __restrict__ bias1,
    const float* __restrict__ bias2,
    bf16_t* __restrict__ Obf, const float* __restrict__ Ares,
    float* __restrict__ Out) {
  __shared__ bf16_t As[2][128 * 32];     // 8 KB per buffer
  __shared__ bf16_t Bs[2][128 * 32];
  const int tid = threadIdx.x;
  const int wave = tid >> 6, lane = tid & 63;
  const int lr = lane & 15, kg4 = lane >> 4;         // k-group 0..3
  const int nwg = (kRows / 128) * GX;
  const int wg = (blockIdx.x & 7) * (nwg >> 3) + (blockIdx.x >> 3);
  const int m0 = (wg / GX) * 128, n0 = (wg % GX) * 128;
  const int wm = (wave >> 1) * 64, wn = (wave & 1) * 64;
  // staging: chunk = 16 rows x 32 cols (1 KB); lane -> row c*16+(l>>2),
  // 16B slot (l&3); global slot pre-swizzled: (l&3)^(row&3)
  const int srow = lane >> 2;
  const int scol = ((lane & 3) ^ (srow & 3)) << 3;   // element offset in row

  auto stage = [&](bf16_t* aDst, bf16_t* bDst, int k0) {
    #pragma unroll
    for (int i = 0; i < 2; ++i) {
      const int c = wave * 2 + i;                    // chunk 0..7
      const int row = c * 16 + srow;
      gload16(Amat + (size_t)(m0 + row) * KDIM + k0 + scol, aDst + c * 512);
      gload16(BT   + (size_t)(n0 + row) * KDIM + k0 + scol, bDst + c * 512);
    }
  };

  f32x4 acc[4][4] = {};
  auto compute = [&](const bf16_t* aSrc, const bf16_t* bSrc) {
    bf16x8 af[4], bq[4];
    #pragma unroll
    for (int m = 0; m < 4; ++m) {
      const int r = wm + m * 16 + lr;
      af[m] = *reinterpret_cast<const bf16x8*>(aSrc + r * 32 + ((kg4 ^ (r & 3)) << 3));
    }
    #pragma unroll
    for (int n = 0; n < 4; ++n) {
      const int r = wn + n * 16 + lr;
      bq[n] = *reinterpret_cast<const bf16x8*>(bSrc + r * 32 + ((kg4 ^ (r & 3)) << 3));
    }
    #pragma unroll
    for (int m = 0; m < 4; ++m)
      #pragma unroll
      for (int n = 0; n < 4; ++n)
        acc[m][n] = __builtin_amdgcn_mfma_f32_16x16x32_bf16(af[m], bq[n], acc[m][n], 0, 0, 0);
  };

  stage(As[0], Bs[0], 0);
  __syncthreads();
  constexpr int NT = KDIM / 32;
  #pragma unroll
  for (int t = 0; t < NT; ++t) {
    if (t + 1 < NT) stage(As[(t + 1) & 1], Bs[(t + 1) & 1], (t + 1) * 32);
    compute(As[t & 1], Bs[t & 1]);
    __syncthreads();
  }

  #pragma unroll
  for (int m = 0; m < 4; ++m) {
    #pragma unroll
    for (int n = 0; n < 4; ++n) {
      #pragma unroll
      for (int r = 0; r < 4; ++r) {
        const int row = m0 + wm + m * 16 + kg4 * 4 + r;
        const int col = n0 + wn + n * 16 + lr;
        float v = acc[m][n][r];
        if constexpr (EPI == 0) {
          const int which = col >> 8, c = col & 255;
          const float* bp = which == 0 ? bias0 : (which == 1 ? bias1 : bias2);
          v += bp[c];
          Obf[(size_t)which * kRows * kC + (size_t)row * kC + c] = __float2bfloat16(v);
        } else if constexpr (EPI == 1) {
          v += bias0[col];
          Obf[(size_t)row * kFF + col] = __float2bfloat16(gelu_fast(v));
        } else {
          v += bias0[col] + Ares[(size_t)row * kC + col];
          int b, g1, g2; row_coords(row, b, g1, g2);
          Out[(((size_t)b * kGRID + g1) * kGRID + g2) * kC + col] = v;
        }
      }
    }
  }
}

// ---------------- MFMA attention (unchanged)
constexpr int kKsPad = 40;
constexpr int kVtPad = 200;
constexpr int kPlPad = 200;
__global__ __launch_bounds__(256) void k_attn(
    const bf16_t* __restrict__ Q, const bf16_t* __restrict__ K,
    const bf16_t* __restrict__ V, const float* __restrict__ pos,
    bf16_t* __restrict__ SA) {
  __shared__ short Ks[kP * kKsPad];
  __shared__ short Vt[kDh * kVtPad];
  __shared__ short Pl[4 * 16 * kPlPad];
  const int bw = blockIdx.x >> 3, h = blockIdx.x & 7;
  const int rowbase = bw * kP, colbase = h * kDh;
  const int tid = threadIdx.x, wave = tid >> 6, lane = tid & 63;
  const int lr = lane & 15, kg = lane >> 4;
  const int wq0 = wave * 48;
  const float* pb = pos + (size_t)h * kP * kP;

  #pragma unroll
  for (int i = 0; i < 3; ++i) {
    const int c = tid + i * 256;
    const int row = c >> 2, dch = (c & 3) * 8;
    const size_t gbase = (size_t)(rowbase + row) * kC + colbase + dch;
    bf16x8 kv = *reinterpret_cast<const bf16x8*>(K + gbase);
    *reinterpret_cast<bf16x8*>(&Ks[row * kKsPad + dch]) = kv;
    bf16x8 vv = *reinterpret_cast<const bf16x8*>(V + gbase);
    #pragma unroll
    for (int e = 0; e < 8; ++e) Vt[(dch + e) * kVtPad + row] = vv[e];
  }
  __syncthreads();

  for (int m = 0; m < 3; ++m) {
    const int rbase = wq0 + m * 16;
    bf16x8 aq = *reinterpret_cast<const bf16x8*>(
        Q + (size_t)(rowbase + rbase + lr) * kC + colbase + kg * 8);
    f32x4 s[12];
    #pragma unroll
    for (int n = 0; n < 12; ++n) {
      bf16x8 bk = *reinterpret_cast<const bf16x8*>(&Ks[(n * 16 + lr) * kKsPad + kg * 8]);
      s[n] = __builtin_amdgcn_mfma_f32_16x16x32_bf16(aq, bk, (f32x4){0.f, 0.f, 0.f, 0.f}, 0, 0, 0);
    }
    float mx[4] = {-1e30f, -1e30f, -1e30f, -1e30f};
    #pragma unroll
    for (int n = 0; n < 12; ++n) {
      #pragma unroll
      for (int r = 0; r < 4; ++r) {
        const float lg = fmaf(s[n][r], kScale,
                              pb[(size_t)(rbase + kg * 4 + r) * kP + n * 16 + lr]);
        s[n][r] = lg;
        mx[r] = fmaxf(mx[r], lg);
      }
    }
    #pragma unroll
    for (int r = 0; r < 4; ++r)
      #pragma unroll
      for (int off = 8; off; off >>= 1) mx[r] = fmaxf(mx[r], __shfl_xor(mx[r], off));
    float sm[4] = {0.f, 0.f, 0.f, 0.f};
    #pragma unroll
    for (int n = 0; n < 12; ++n)
      #pragma unroll
      for (int r = 0; r < 4; ++r) {
        const float e = __expf(s[n][r] - mx[r]);
        s[n][r] = e;
        sm[r] += e;
      }
    #pragma unroll
    for (int r = 0; r < 4; ++r) {
      #pragma unroll
      for (int off = 8; off; off >>= 1) sm[r] += __shfl_xor(sm[r], off);
      sm[r] = 1.f / sm[r];
    }
    #pragma unroll
    for (int n = 0; n < 12; ++n)
      #pragma unroll
      for (int r = 0; r < 4; ++r)
        Pl[(wave * 16 + kg * 4 + r) * kPlPad + n * 16 + lr] = f2bf(s[n][r] * sm[r]);
    f32x4 o0 = {0.f, 0.f, 0.f, 0.f}, o1 = {0.f, 0.f, 0.f, 0.f};
    #pragma unroll
    for (int kk = 0; kk < 6; ++kk) {
      bf16x8 ap = *reinterpret_cast<const bf16x8*>(&Pl[(wave * 16 + lr) * kPlPad + kk * 32 + kg * 8]);
      bf16x8 b0 = *reinterpret_cast<const bf16x8*>(&Vt[lr * kVtPad + kk * 32 + kg * 8]);
      bf16x8 b1 = *reinterpret_cast<const bf16x8*>(&Vt[(16 + lr) * kVtPad + kk * 32 + kg * 8]);
      o0 = __builtin_amdgcn_mfma_f32_16x16x32_bf16(ap, b0, o0, 0, 0, 0);
      o1 = __builtin_amdgcn_mfma_f32_16x16x32_bf16(ap, b1, o1, 0, 0, 0);
    }
    bf16_t* sp = SA + (size_t)(rowbase + rbase + kg * 4) * kC + colbase;
    #pragma unroll
    for (int r = 0; r < 4; ++r) {
      sp[(size_t)r * kC + lr]      = __float2bfloat16(o0[r]);
      sp[(size_t)r * kC + 16 + lr] = __float2bfloat16(o1[r]);
    }
  }
}

extern "C" void kernel_launch(void* const* d_in, const int* in_sizes, int n_in,
                              void* d_out, int out_size, void* d_ws, size_t ws_size,
                              hipStream_t stream) {
  const float* emb  = (const float*)d_in[0];
  const float* ln1g = (const float*)d_in[1];
  const float* ln1b = (const float*)d_in[2];
  const float* wq   = (const float*)d_in[3];
  const float* bq   = (const float*)d_in[4];
  const float* wk   = (const float*)d_in[5];
  const float* bk   = (const float*)d_in[6];
  const float* wv   = (const float*)d_in[7];
  const float* bv   = (const float*)d_in[8];
  const float* pos  = (const float*)d_in[9];
  const float* ln2g = (const float*)d_in[10];
  const float* ln2b = (const float*)d_in[11];
  const float* w1   = (const float*)d_in[12];
  const float* b1   = (const float*)d_in[13];
  const float* w2   = (const float*)d_in[14];
  const float* b2   = (const float*)d_in[15];

  char* ws = (char*)d_ws;
  const size_t nYb = (size_t)kRows * kC * 2;               // 18,874,368 B
  bf16_t* Y    = (bf16_t*)(ws);                            // [0, 18.9M)
  bf16_t* Qb   = (bf16_t*)(ws + nYb);                      // Q,K,V consecutive
  bf16_t* SAb  = (bf16_t*)(ws + nYb * 4);                  // [75.5M, 94.4M)
  float*  Abuf = (float*) (ws + nYb * 5);                  // [94.4M, 132.1M)
  bf16_t* H    = (bf16_t*)(ws + nYb * 5 + (size_t)kRows * kC * 4);  // [132.1M, 151M)
  bf16_t* G    = (bf16_t*)(ws);                            // alias dead Y/Q/K/V
  bf16_t* W    = (bf16_t*)(ws + nYb * 5 + (size_t)kRows * kC * 4 + nYb);
  bf16_t* WqkvT = W;
  bf16_t* W1T   = W + 768 * 256;
  bf16_t* W2T   = W1T + 1024 * 256;

  k_wconv<<<2816, 256, 0, stream>>>(wq, wk, wv, w1, w2, W);
  k_ln1<<<kRows / 8, 256, 0, stream>>>(emb, ln1g, ln1b, Y);
  k_gemm3<256, 0, 6><<<(kRows / 128) * 6, 256, 0, stream>>>(
      Y, WqkvT, bq, bk, bv, Qb, nullptr, nullptr);
  k_attn<<<kB * kNW * kNH, 256, 0, stream>>>(
      Qb, Qb + (size_t)kRows * kC, Qb + 2 * (size_t)kRows * kC, pos, SAb);
  k_ln2<<<kRows / 8, 256, 0, stream>>>(emb, SAb, ln2g, ln2b, Abuf, H);
  k_gemm3<256, 1, 8><<<(kRows / 128) * 8, 256, 0, stream>>>(
      H, W1T, b1, nullptr, nullptr, G, nullptr, nullptr);
  k_gemm3<1024, 2, 2><<<(kRows / 128) * 2, 256, 0, stream>>>(
      G, W2T, b2, nullptr, nullptr, nullptr, Abuf, (float*)d_out);
}

// Round 11
// 184.092 us; speedup vs baseline: 3.5737x; 1.0493x over previous
//
#include <hip/hip_runtime.h>
#include <hip/hip_bf16.h>
#include <cstdint>

using bf16x8 = __attribute__((ext_vector_type(8))) short;
using f32x4  = __attribute__((ext_vector_type(4))) float;
using bf16_t = __hip_bfloat16;

#define DEVI static __device__ __forceinline__

constexpr int kB = 4, kC = 256, kNH = 8, kDh = 32;
constexpr int kVP = 6, kVW = 16, kHP = 32, kHW = 3;
constexpr int kNW = 48, kP = 192, kGRID = 96;
constexpr int kRows = kB * kNW * kP;    // 36864
constexpr int kFF = 1024;
constexpr float kScale = 0.0625f;       // 1/sqrt(C)

DEVI void row_coords(int row, int& b, int& g1, int& g2) {
  int b_  = row / (kNW * kP);
  int rem = row - b_ * (kNW * kP);
  int w = rem / kP;
  int p = rem - w * kP;
  int vw = w / kHW, hw = w - vw * kHW;
  int vp = p >> 5,  hp = p & 31;
  int r  = vp * kVW + vw;
  int cc = hp * kHW + hw;
  g1 = r + 80;  if (g1 >= kGRID) g1 -= kGRID;
  g2 = cc + 93; if (g2 >= kGRID) g2 -= kGRID;
  b = b_;
}

DEVI float bf2f(short s) {
  union { unsigned u; float f; } c;
  c.u = ((unsigned)(unsigned short)s) << 16;
  return c.f;
}
DEVI short f2bf(float f) {
  bf16_t h = __float2bfloat16(f);
  return *reinterpret_cast<short*>(&h);
}

DEVI void gload16(const void* g, void* l) {
  __builtin_amdgcn_global_load_lds(
      (__attribute__((address_space(1))) void*)(uintptr_t)g,
      (__attribute__((address_space(3))) void*)(uintptr_t)l, 16, 0, 0);
}

DEVI float gelu_fast(float v) {
  // tanh-form GELU via expf (validated R9/R10: pipeline absmax 0.03125).
  const float t = v * 0.7978845608f * (1.f + 0.044715f * v * v);
  const float e = __expf(fminf(-2.f * t, 60.f));
  return 0.5f * v * (1.f + (1.f - e) / (1.f + e));
}

// ---------------- weight convert
__global__ __launch_bounds__(256) void k_wconv(
    const float* __restrict__ wq, const float* __restrict__ wk,
    const float* __restrict__ wv, const float* __restrict__ w1,
    const float* __restrict__ w2, bf16_t* __restrict__ W) {
  const int i = blockIdx.x * 256 + threadIdx.x;
  if (i < 196608) {                       // WqkvT: n*256+k
    const int n = i >> 8, k = i & 255;
    const float* src = n < 256 ? wq : (n < 512 ? wk : wv);
    W[i] = __float2bfloat16(src[k * 256 + (n & 255)]);
  } else if (i < 458752) {                // W1T: n*256+k, n<1024
    const int j = i - 196608;
    const int n = j >> 8, k = j & 255;
    W[i] = __float2bfloat16(w1[k * 1024 + n]);
  } else if (i < 720896) {                // W2T: n*1024+k, n<256
    const int j = i - 458752;
    const int n = j >> 10, k = j & 1023;
    W[i] = __float2bfloat16(w2[k * 256 + n]);
  }
}

// ---------------- gather + LN1 -> Y bf16
__global__ __launch_bounds__(256) void k_ln1(const float* __restrict__ emb,
    const float* __restrict__ gam, const float* __restrict__ bet,
    bf16_t* __restrict__ Y) {
  const int wave = threadIdx.x >> 6, lane = threadIdx.x & 63;
  #pragma unroll
  for (int rr = 0; rr < 2; ++rr) {
    const int row = blockIdx.x * 8 + wave * 2 + rr;
    int b, g1, g2; row_coords(row, b, g1, g2);
    const float* src = emb + (((size_t)b * kGRID + g1) * kGRID + g2) * kC;
    float4 x = *reinterpret_cast<const float4*>(src + lane * 4);
    float s  = x.x + x.y + x.z + x.w;
    float sq = x.x*x.x + x.y*x.y + x.z*x.z + x.w*x.w;
    #pragma unroll
    for (int off = 32; off; off >>= 1) { s += __shfl_xor(s, off); sq += __shfl_xor(sq, off); }
    const float mean = s * (1.f / kC);
    const float rstd = rsqrtf(sq * (1.f / kC) - mean * mean + 1e-5f);
    const float4 g4 = *reinterpret_cast<const float4*>(gam + lane * 4);
    const float4 b4 = *reinterpret_cast<const float4*>(bet + lane * 4);
    short4 o;
    o.x = f2bf((x.x - mean) * rstd * g4.x + b4.x);
    o.y = f2bf((x.y - mean) * rstd * g4.y + b4.y);
    o.z = f2bf((x.z - mean) * rstd * g4.z + b4.z);
    o.w = f2bf((x.w - mean) * rstd * g4.w + b4.w);
    *reinterpret_cast<short4*>(Y + (size_t)row * kC + lane * 4) = o;
  }
}

// ---------------- re-gather + residual + LN2 -> A fp32, H bf16
__global__ __launch_bounds__(256) void k_ln2(const float* __restrict__ emb,
    const bf16_t* __restrict__ SA,
    const float* __restrict__ gam, const float* __restrict__ bet,
    float* __restrict__ A, bf16_t* __restrict__ H) {
  const int wave = threadIdx.x >> 6, lane = threadIdx.x & 63;
  #pragma unroll
  for (int rr = 0; rr < 2; ++rr) {
    const int row = blockIdx.x * 8 + wave * 2 + rr;
    int b, g1, g2; row_coords(row, b, g1, g2);
    const float* src = emb + (((size_t)b * kGRID + g1) * kGRID + g2) * kC;
    float4 x = *reinterpret_cast<const float4*>(src + lane * 4);
    short4 sv = *reinterpret_cast<const short4*>(SA + (size_t)row * kC + lane * 4);
    x.x += bf2f(sv.x); x.y += bf2f(sv.y); x.z += bf2f(sv.z); x.w += bf2f(sv.w);
    *reinterpret_cast<float4*>(A + (size_t)row * kC + lane * 4) = x;
    float s  = x.x + x.y + x.z + x.w;
    float sq = x.x*x.x + x.y*x.y + x.z*x.z + x.w*x.w;
    #pragma unroll
    for (int off = 32; off; off >>= 1) { s += __shfl_xor(s, off); sq += __shfl_xor(sq, off); }
    const float mean = s * (1.f / kC);
    const float rstd = rsqrtf(sq * (1.f / kC) - mean * mean + 1e-5f);
    const float4 g4 = *reinterpret_cast<const float4*>(gam + lane * 4);
    const float4 b4 = *reinterpret_cast<const float4*>(bet + lane * 4);
    short4 o;
    o.x = f2bf((x.x - mean) * rstd * g4.x + b4.x);
    o.y = f2bf((x.y - mean) * rstd * g4.y + b4.y);
    o.z = f2bf((x.z - mean) * rstd * g4.z + b4.z);
    o.w = f2bf((x.w - mean) * rstd * g4.w + b4.w);
    *reinterpret_cast<short4*>(H + (size_t)row * kC + lane * 4) = o;
  }
}

// ---------------- MFMA GEMM (R10 main loop; NEW coalesced LDS-transpose
// epilogue). 128x128 tile, BK=32 dbuf (32 KB), 4 waves (2x2), wave 64x64,
// __launch_bounds__(256,4). After the K-loop each wave stages its 64x64 tile
// into its private 8KB LDS slice (scalar LDS writes = LGKM pipe), then issues
// 8 WIDE 16B global stores per thread (vs 64 scalar 2B stores). This attacks
// the measured invariant: FFN1 pinned at 71-87us across 5 main-loop
// structures = VMEM store-issue bound (37.7M scalar stores ~= 61us at
// 1 instr/cyc/CU).
template <int KDIM, int EPI, int GX>
__global__ __launch_bounds__(256, 4) void k_gemm3(
    const bf16_t* __restrict__ Amat, const bf16_t* __restrict__ BT,
    const float* __restrict__ bias0, const float* __restrict__ bias1,
    const float* __restrict__ bias2,
    bf16_t* __restrict__ Obf, const float* __restrict__ Ares,
    float* __restrict__ Out) {
  __shared__ short sm[16384];            // 32 KB: As[2] | Bs[2], then scratch
  bf16_t* const As0 = (bf16_t*)&sm[0];
  bf16_t* const As1 = (bf16_t*)&sm[4096];
  bf16_t* const Bs0 = (bf16_t*)&sm[8192];
  bf16_t* const Bs1 = (bf16_t*)&sm[12288];
  const int tid = threadIdx.x;
  const int wave = tid >> 6, lane = tid & 63;
  const int lr = lane & 15, kg4 = lane >> 4;         // k-group 0..3
  const int nwg = (kRows / 128) * GX;
  const int wg = (blockIdx.x & 7) * (nwg >> 3) + (blockIdx.x >> 3);
  const int m0 = (wg / GX) * 128, n0 = (wg % GX) * 128;
  const int wm = (wave >> 1) * 64, wn = (wave & 1) * 64;
  const int srow = lane >> 2;
  const int scol = ((lane & 3) ^ (srow & 3)) << 3;   // pre-swizzled 16B slot

  auto stage = [&](bf16_t* aDst, bf16_t* bDst, int k0) {
    #pragma unroll
    for (int i = 0; i < 2; ++i) {
      const int c = wave * 2 + i;                    // chunk 0..7
      const int row = c * 16 + srow;
      gload16(Amat + (size_t)(m0 + row) * KDIM + k0 + scol, aDst + c * 512);
      gload16(BT   + (size_t)(n0 + row) * KDIM + k0 + scol, bDst + c * 512);
    }
  };

  f32x4 acc[4][4] = {};
  auto compute = [&](const bf16_t* aSrc, const bf16_t* bSrc) {
    bf16x8 af[4], bq[4];
    #pragma unroll
    for (int m = 0; m < 4; ++m) {
      const int r = wm + m * 16 + lr;
      af[m] = *reinterpret_cast<const bf16x8*>(aSrc + r * 32 + ((kg4 ^ (r & 3)) << 3));
    }
    #pragma unroll
    for (int n = 0; n < 4; ++n) {
      const int r = wn + n * 16 + lr;
      bq[n] = *reinterpret_cast<const bf16x8*>(bSrc + r * 32 + ((kg4 ^ (r & 3)) << 3));
    }
    #pragma unroll
    for (int m = 0; m < 4; ++m)
      #pragma unroll
      for (int n = 0; n < 4; ++n)
        acc[m][n] = __builtin_amdgcn_mfma_f32_16x16x32_bf16(af[m], bq[n], acc[m][n], 0, 0, 0);
  };

  stage(As0, Bs0, 0);
  __syncthreads();
  constexpr int NT = KDIM / 32;
  #pragma unroll
  for (int t = 0; t < NT; ++t) {
    if (t + 1 < NT) stage(((t + 1) & 1) ? As1 : As0, ((t + 1) & 1) ? Bs1 : Bs0,
                          (t + 1) * 32);
    compute((t & 1) ? As1 : As0, (t & 1) ? Bs1 : Bs0);
    __syncthreads();
  }
  // all compute done (final barrier above) -> LDS reusable as scratch.

  if constexpr (EPI == 0 || EPI == 1) {
    short* scr = &sm[wave * 4096];                   // 64x64 bf16, rows 128B
    const int colbase = n0 + wn;
    const float* bp;
    int cb;                                          // col base within output
    if constexpr (EPI == 0) {
      const int which = colbase >> 8;
      bp = which == 0 ? bias0 : (which == 1 ? bias1 : bias2);
      cb = colbase & 255;
    } else { bp = bias0; cb = colbase; }
    #pragma unroll
    for (int m = 0; m < 4; ++m)
      #pragma unroll
      for (int n = 0; n < 4; ++n)
        #pragma unroll
        for (int r = 0; r < 4; ++r) {
          const int lrow = m * 16 + kg4 * 4 + r;
          const int lcol = n * 16 + lr;
          float v = acc[m][n][r] + bp[cb + lcol];
          if constexpr (EPI == 1) v = gelu_fast(v);
          scr[lrow * 64 + lcol] = f2bf(v);
        }
    const int rl = lane >> 3, cl = (lane & 7) * 8;   // 8 lanes/row, 16B/lane
    bf16_t* const obase = (EPI == 0)
        ? Obf + (size_t)(colbase >> 8) * kRows * kC
        : Obf;
    const int ld = (EPI == 0) ? kC : kFF;
    #pragma unroll
    for (int p = 0; p < 8; ++p) {
      const int lrow = p * 8 + rl;
      bf16x8 v = *reinterpret_cast<const bf16x8*>(&scr[lrow * 64 + cl]);
      *reinterpret_cast<bf16x8*>(
          obase + (size_t)(m0 + wm + lrow) * ld + cb + cl) = v;
    }
  } else {
    float* scrf = reinterpret_cast<float*>(&sm[wave * 4096]);  // 64x32 f32
    #pragma unroll
    for (int h = 0; h < 2; ++h) {
      #pragma unroll
      for (int m = 0; m < 4; ++m)
        #pragma unroll
        for (int nn = 0; nn < 2; ++nn) {
          const int n = h * 2 + nn;
          #pragma unroll
          for (int r = 0; r < 4; ++r)
            scrf[(m * 16 + kg4 * 4 + r) * 32 + nn * 16 + lr] =
                acc[m][n][r] + bias0[n0 + wn + n * 16 + lr];
        }
      const int rl = lane >> 3, cl = (lane & 7) * 4; // 8 lanes/row, 16B/lane
      #pragma unroll
      for (int p = 0; p < 8; ++p) {
        const int lrow = p * 8 + rl;
        const int row = m0 + wm + lrow;
        const int col = n0 + wn + h * 32 + cl;
        float4 v = *reinterpret_cast<const float4*>(&scrf[lrow * 32 + cl]);
        const float4 a4 = *reinterpret_cast<const float4*>(
            &Ares[(size_t)row * kC + col]);
        v.x += a4.x; v.y += a4.y; v.z += a4.z; v.w += a4.w;
        int b, g1, g2; row_coords(row, b, g1, g2);
        *reinterpret_cast<float4*>(
            &Out[(((size_t)b * kGRID + g1) * kGRID + g2) * kC + col]) = v;
      }
    }
  }
}

// ---------------- MFMA attention (R2 structure + coalesced store epilogue)
constexpr int kKsPad = 40;
constexpr int kVtPad = 200;
constexpr int kPlPad = 200;
__global__ __launch_bounds__(256) void k_attn(
    const bf16_t* __restrict__ Q, const bf16_t* __restrict__ K,
    const bf16_t* __restrict__ V, const float* __restrict__ pos,
    bf16_t* __restrict__ SA) {
  __shared__ short Ks[kP * kKsPad];
  __shared__ short Vt[kDh * kVtPad];
  __shared__ short Pl[4 * 16 * kPlPad];
  const int bw = blockIdx.x >> 3, h = blockIdx.x & 7;
  const int rowbase = bw * kP, colbase = h * kDh;
  const int tid = threadIdx.x, wave = tid >> 6, lane = tid & 63;
  const int lr = lane & 15, kg = lane >> 4;
  const int wq0 = wave * 48;
  const float* pb = pos + (size_t)h * kP * kP;

  #pragma unroll
  for (int i = 0; i < 3; ++i) {
    const int c = tid + i * 256;
    const int row = c >> 2, dch = (c & 3) * 8;
    const size_t gbase = (size_t)(rowbase + row) * kC + colbase + dch;
    bf16x8 kv = *reinterpret_cast<const bf16x8*>(K + gbase);
    *reinterpret_cast<bf16x8*>(&Ks[row * kKsPad + dch]) = kv;
    bf16x8 vv = *reinterpret_cast<const bf16x8*>(V + gbase);
    #pragma unroll
    for (int e = 0; e < 8; ++e) Vt[(dch + e) * kVtPad + row] = vv[e];
  }
  __syncthreads();

  for (int m = 0; m < 3; ++m) {
    const int rbase = wq0 + m * 16;
    bf16x8 aq = *reinterpret_cast<const bf16x8*>(
        Q + (size_t)(rowbase + rbase + lr) * kC + colbase + kg * 8);
    f32x4 s[12];
    #pragma unroll
    for (int n = 0; n < 12; ++n) {
      bf16x8 bk = *reinterpret_cast<const bf16x8*>(&Ks[(n * 16 + lr) * kKsPad + kg * 8]);
      s[n] = __builtin_amdgcn_mfma_f32_16x16x32_bf16(aq, bk, (f32x4){0.f, 0.f, 0.f, 0.f}, 0, 0, 0);
    }
    float mx[4] = {-1e30f, -1e30f, -1e30f, -1e30f};
    #pragma unroll
    for (int n = 0; n < 12; ++n) {
      #pragma unroll
      for (int r = 0; r < 4; ++r) {
        const float lg = fmaf(s[n][r], kScale,
                              pb[(size_t)(rbase + kg * 4 + r) * kP + n * 16 + lr]);
        s[n][r] = lg;
        mx[r] = fmaxf(mx[r], lg);
      }
    }
    #pragma unroll
    for (int r = 0; r < 4; ++r)
      #pragma unroll
      for (int off = 8; off; off >>= 1) mx[r] = fmaxf(mx[r], __shfl_xor(mx[r], off));
    float sm4[4] = {0.f, 0.f, 0.f, 0.f};
    #pragma unroll
    for (int n = 0; n < 12; ++n)
      #pragma unroll
      for (int r = 0; r < 4; ++r) {
        const float e = __expf(s[n][r] - mx[r]);
        s[n][r] = e;
        sm4[r] += e;
      }
    #pragma unroll
    for (int r = 0; r < 4; ++r) {
      #pragma unroll
      for (int off = 8; off; off >>= 1) sm4[r] += __shfl_xor(sm4[r], off);
      sm4[r] = 1.f / sm4[r];
    }
    #pragma unroll
    for (int n = 0; n < 12; ++n)
      #pragma unroll
      for (int r = 0; r < 4; ++r)
        Pl[(wave * 16 + kg * 4 + r) * kPlPad + n * 16 + lr] = f2bf(s[n][r] * sm4[r]);
    f32x4 o0 = {0.f, 0.f, 0.f, 0.f}, o1 = {0.f, 0.f, 0.f, 0.f};
    #pragma unroll
    for (int kk = 0; kk < 6; ++kk) {
      bf16x8 ap = *reinterpret_cast<const bf16x8*>(&Pl[(wave * 16 + lr) * kPlPad + kk * 32 + kg * 8]);
      bf16x8 b0 = *reinterpret_cast<const bf16x8*>(&Vt[lr * kVtPad + kk * 32 + kg * 8]);
      bf16x8 b1 = *reinterpret_cast<const bf16x8*>(&Vt[(16 + lr) * kVtPad + kk * 32 + kg * 8]);
      o0 = __builtin_amdgcn_mfma_f32_16x16x32_bf16(ap, b0, o0, 0, 0, 0);
      o1 = __builtin_amdgcn_mfma_f32_16x16x32_bf16(ap, b1, o1, 0, 0, 0);
    }
    // coalesced store: stage 16x32 tile in this wave's Pl slice, one wide
    // 16B store per lane (was 24 scalar 2B stores/thread per kernel).
    short* scr2 = &Pl[wave * 16 * kPlPad];
    #pragma unroll
    for (int r = 0; r < 4; ++r) {
      scr2[(kg * 4 + r) * 32 + lr]      = f2bf(o0[r]);
      scr2[(kg * 4 + r) * 32 + 16 + lr] = f2bf(o1[r]);
    }
    {
      const int rrow = lane >> 2, c0 = (lane & 3) * 8;
      bf16x8 v = *reinterpret_cast<const bf16x8*>(&scr2[rrow * 32 + c0]);
      *reinterpret_cast<bf16x8*>(
          SA + (size_t)(rowbase + rbase + rrow) * kC + colbase + c0) = v;
    }
  }
}

extern "C" void kernel_launch(void* const* d_in, const int* in_sizes, int n_in,
                              void* d_out, int out_size, void* d_ws, size_t ws_size,
                              hipStream_t stream) {
  const float* emb  = (const float*)d_in[0];
  const float* ln1g = (const float*)d_in[1];
  const float* ln1b = (const float*)d_in[2];
  const float* wq   = (const float*)d_in[3];
  const float* bq   = (const float*)d_in[4];
  const float* wk   = (const float*)d_in[5];
  const float* bk   = (const float*)d_in[6];
  const float* wv   = (const float*)d_in[7];
  const float* bv   = (const float*)d_in[8];
  const float* pos  = (const float*)d_in[9];
  const float* ln2g = (const float*)d_in[10];
  const float* ln2b = (const float*)d_in[11];
  const float* w1   = (const float*)d_in[12];
  const float* b1   = (const float*)d_in[13];
  const float* w2   = (const float*)d_in[14];
  const float* b2   = (const float*)d_in[15];

  char* ws = (char*)d_ws;
  const size_t nYb = (size_t)kRows * kC * 2;               // 18,874,368 B
  bf16_t* Y    = (bf16_t*)(ws);                            // [0, 18.9M)
  bf16_t* Qb   = (bf16_t*)(ws + nYb);                      // Q,K,V consecutive
  bf16_t* SAb  = (bf16_t*)(ws + nYb * 4);                  // [75.5M, 94.4M)
  float*  Abuf = (float*) (ws + nYb * 5);                  // [94.4M, 132.1M)
  bf16_t* H    = (bf16_t*)(ws + nYb * 5 + (size_t)kRows * kC * 4);  // [132.1M, 151M)
  bf16_t* G    = (bf16_t*)(ws);                            // alias dead Y/Q/K/V
  bf16_t* W    = (bf16_t*)(ws + nYb * 5 + (size_t)kRows * kC * 4 + nYb);
  bf16_t* WqkvT = W;
  bf16_t* W1T   = W + 768 * 256;
  bf16_t* W2T   = W1T + 1024 * 256;

  k_wconv<<<2816, 256, 0, stream>>>(wq, wk, wv, w1, w2, W);
  k_ln1<<<kRows / 8, 256, 0, stream>>>(emb, ln1g, ln1b, Y);
  k_gemm3<256, 0, 6><<<(kRows / 128) * 6, 256, 0, stream>>>(
      Y, WqkvT, bq, bk, bv, Qb, nullptr, nullptr);
  k_attn<<<kB * kNW * kNH, 256, 0, stream>>>(
      Qb, Qb + (size_t)kRows * kC, Qb + 2 * (size_t)kRows * kC, pos, SAb);
  k_ln2<<<kRows / 8, 256, 0, stream>>>(emb, SAb, ln2g, ln2b, Abuf, H);
  k_gemm3<256, 1, 8><<<(kRows / 128) * 8, 256, 0, stream>>>(
      H, W1T, b1, nullptr, nullptr, G, nullptr, nullptr);
  k_gemm3<1024, 2, 2><<<(kRows / 128) * 2, 256, 0, stream>>>(
      G, W2T, b2, nullptr, nullptr, nullptr, Abuf, (float*)d_out);
}

// Round 12
// 177.278 us; speedup vs baseline: 3.7111x; 1.0384x over previous
//
#include <hip/hip_runtime.h>
#include <hip/hip_bf16.h>
#include <cstdint>

using bf16x8 = __attribute__((ext_vector_type(8))) short;
using f32x4  = __attribute__((ext_vector_type(4))) float;
using bf16_t = __hip_bfloat16;

#define DEVI static __device__ __forceinline__

constexpr int kB = 4, kC = 256, kNH = 8, kDh = 32;
constexpr int kVP = 6, kVW = 16, kHP = 32, kHW = 3;
constexpr int kNW = 48, kP = 192, kGRID = 96;
constexpr int kRows = kB * kNW * kP;    // 36864
constexpr int kFF = 1024;
constexpr float kScale = 0.0625f;       // 1/sqrt(C)

DEVI void row_coords(int row, int& b, int& g1, int& g2) {
  int b_  = row / (kNW * kP);
  int rem = row - b_ * (kNW * kP);
  int w = rem / kP;
  int p = rem - w * kP;
  int vw = w / kHW, hw = w - vw * kHW;
  int vp = p >> 5,  hp = p & 31;
  int r  = vp * kVW + vw;
  int cc = hp * kHW + hw;
  g1 = r + 80;  if (g1 >= kGRID) g1 -= kGRID;
  g2 = cc + 93; if (g2 >= kGRID) g2 -= kGRID;
  b = b_;
}

DEVI float bf2f(short s) {
  union { unsigned u; float f; } c;
  c.u = ((unsigned)(unsigned short)s) << 16;
  return c.f;
}
DEVI short f2bf(float f) {
  bf16_t h = __float2bfloat16(f);
  return *reinterpret_cast<short*>(&h);
}

DEVI void gload16(const void* g, void* l) {
  __builtin_amdgcn_global_load_lds(
      (__attribute__((address_space(1))) void*)(uintptr_t)g,
      (__attribute__((address_space(3))) void*)(uintptr_t)l, 16, 0, 0);
}

// asm ds_read_b128: LDS byte offset in a VGPR. Opaque to SIInsertWaitcnts so
// the compiler cannot attach a conservative vmcnt(0) drain to it — this is
// what makes the counted vmcnt below actually govern the pipeline (m131/m218:
// builtin ds_read gets compiler-inserted vmcnt(0) for global_load_lds data).
DEVI bf16x8 ds_read_b128(uint32_t byte_off) {
  bf16x8 v;
  asm volatile("ds_read_b128 %0, %1" : "=v"(v) : "v"(byte_off));
  return v;
}

DEVI float gelu_fast(float v) {
  // sigmoid form of tanh-GELU: 0.5v(1+tanh(t)) == v/(1+exp(-2t)).
  // Identical math to R9-R11's validated gelu (absmax 0.03125), ~half VALU.
  const float t2 = v * 1.5957691216f * (1.f + 0.044715f * v * v);  // 2t
  return v / (1.f + __expf(fminf(-t2, 60.f)));
}

// ---------------- weight convert
__global__ __launch_bounds__(256) void k_wconv(
    const float* __restrict__ wq, const float* __restrict__ wk,
    const float* __restrict__ wv, const float* __restrict__ w1,
    const float* __restrict__ w2, bf16_t* __restrict__ W) {
  const int i = blockIdx.x * 256 + threadIdx.x;
  if (i < 196608) {                       // WqkvT: n*256+k
    const int n = i >> 8, k = i & 255;
    const float* src = n < 256 ? wq : (n < 512 ? wk : wv);
    W[i] = __float2bfloat16(src[k * 256 + (n & 255)]);
  } else if (i < 458752) {                // W1T: n*256+k, n<1024
    const int j = i - 196608;
    const int n = j >> 8, k = j & 255;
    W[i] = __float2bfloat16(w1[k * 1024 + n]);
  } else if (i < 720896) {                // W2T: n*1024+k, n<256
    const int j = i - 458752;
    const int n = j >> 10, k = j & 1023;
    W[i] = __float2bfloat16(w2[k * 256 + n]);
  }
}

// ---------------- gather + LN1 -> Y bf16
__global__ __launch_bounds__(256) void k_ln1(const float* __restrict__ emb,
    const float* __restrict__ gam, const float* __restrict__ bet,
    bf16_t* __restrict__ Y) {
  const int wave = threadIdx.x >> 6, lane = threadIdx.x & 63;
  #pragma unroll
  for (int rr = 0; rr < 2; ++rr) {
    const int row = blockIdx.x * 8 + wave * 2 + rr;
    int b, g1, g2; row_coords(row, b, g1, g2);
    const float* src = emb + (((size_t)b * kGRID + g1) * kGRID + g2) * kC;
    float4 x = *reinterpret_cast<const float4*>(src + lane * 4);
    float s  = x.x + x.y + x.z + x.w;
    float sq = x.x*x.x + x.y*x.y + x.z*x.z + x.w*x.w;
    #pragma unroll
    for (int off = 32; off; off >>= 1) { s += __shfl_xor(s, off); sq += __shfl_xor(sq, off); }
    const float mean = s * (1.f / kC);
    const float rstd = rsqrtf(sq * (1.f / kC) - mean * mean + 1e-5f);
    const float4 g4 = *reinterpret_cast<const float4*>(gam + lane * 4);
    const float4 b4 = *reinterpret_cast<const float4*>(bet + lane * 4);
    short4 o;
    o.x = f2bf((x.x - mean) * rstd * g4.x + b4.x);
    o.y = f2bf((x.y - mean) * rstd * g4.y + b4.y);
    o.z = f2bf((x.z - mean) * rstd * g4.z + b4.z);
    o.w = f2bf((x.w - mean) * rstd * g4.w + b4.w);
    *reinterpret_cast<short4*>(Y + (size_t)row * kC + lane * 4) = o;
  }
}

// ---------------- re-gather + residual + LN2 -> A fp32, H bf16
__global__ __launch_bounds__(256) void k_ln2(const float* __restrict__ emb,
    const bf16_t* __restrict__ SA,
    const float* __restrict__ gam, const float* __restrict__ bet,
    float* __restrict__ A, bf16_t* __restrict__ H) {
  const int wave = threadIdx.x >> 6, lane = threadIdx.x & 63;
  #pragma unroll
  for (int rr = 0; rr < 2; ++rr) {
    const int row = blockIdx.x * 8 + wave * 2 + rr;
    int b, g1, g2; row_coords(row, b, g1, g2);
    const float* src = emb + (((size_t)b * kGRID + g1) * kGRID + g2) * kC;
    float4 x = *reinterpret_cast<const float4*>(src + lane * 4);
    short4 sv = *reinterpret_cast<const short4*>(SA + (size_t)row * kC + lane * 4);
    x.x += bf2f(sv.x); x.y += bf2f(sv.y); x.z += bf2f(sv.z); x.w += bf2f(sv.w);
    *reinterpret_cast<float4*>(A + (size_t)row * kC + lane * 4) = x;
    float s  = x.x + x.y + x.z + x.w;
    float sq = x.x*x.x + x.y*x.y + x.z*x.z + x.w*x.w;
    #pragma unroll
    for (int off = 32; off; off >>= 1) { s += __shfl_xor(s, off); sq += __shfl_xor(sq, off); }
    const float mean = s * (1.f / kC);
    const float rstd = rsqrtf(sq * (1.f / kC) - mean * mean + 1e-5f);
    const float4 g4 = *reinterpret_cast<const float4*>(gam + lane * 4);
    const float4 b4 = *reinterpret_cast<const float4*>(bet + lane * 4);
    short4 o;
    o.x = f2bf((x.x - mean) * rstd * g4.x + b4.x);
    o.y = f2bf((x.y - mean) * rstd * g4.y + b4.y);
    o.z = f2bf((x.z - mean) * rstd * g4.z + b4.z);
    o.w = f2bf((x.w - mean) * rstd * g4.w + b4.w);
    *reinterpret_cast<short4*>(H + (size_t)row * kC + lane * 4) = o;
  }
}

// ---------------- MFMA GEMM: R10/R11 geometry (128x128, BK=32 dbuf, 4 waves,
// 4 blk/CU) with the sync path rebuilt so counted vmcnt is REAL:
//   stage(t+1) -> asm vmcnt(4) (own t-loads done; t+1's 4 in flight across
//   the barrier) -> s_barrier -> asm ds_read_b128 x8 -> lgkmcnt(0) +
//   sched_barrier (rule #18) -> 16 MFMA (setprio) -> s_barrier.
// Epilogues: R11 wide-store (LDS transpose); EPI1 scratch now XOR-swizzled
// (R11's +1.2M bank conflicts came from un-swizzled 128B-stride scr writes).
template <int KDIM, int EPI, int GX>
__global__ __launch_bounds__(256, 4) void k_gemm6(
    const bf16_t* __restrict__ Amat, const bf16_t* __restrict__ BT,
    const float* __restrict__ bias0, const float* __restrict__ bias1,
    const float* __restrict__ bias2,
    bf16_t* __restrict__ Obf, const float* __restrict__ Ares,
    float* __restrict__ Out) {
  __shared__ short sm[16384];            // 32 KB: As[2] | Bs[2], then scratch
  bf16_t* const As0 = (bf16_t*)&sm[0];
  bf16_t* const As1 = (bf16_t*)&sm[4096];
  bf16_t* const Bs0 = (bf16_t*)&sm[8192];
  bf16_t* const Bs1 = (bf16_t*)&sm[12288];
  const int tid = threadIdx.x;
  const int wave = tid >> 6, lane = tid & 63;
  const int lr = lane & 15, kg4 = lane >> 4;         // k-group 0..3
  const int nwg = (kRows / 128) * GX;
  const int wg = (blockIdx.x & 7) * (nwg >> 3) + (blockIdx.x >> 3);
  const int m0 = (wg / GX) * 128, n0 = (wg % GX) * 128;
  const int wm = (wave >> 1) * 64, wn = (wave & 1) * 64;
  const int srow = lane >> 2;
  const int scol = ((lane & 3) ^ (srow & 3)) << 3;   // pre-swizzled 16B slot

  auto stage = [&](bf16_t* aDst, bf16_t* bDst, int k0) {
    #pragma unroll
    for (int i = 0; i < 2; ++i) {
      const int c = wave * 2 + i;                    // chunk 0..7
      const int row = c * 16 + srow;
      gload16(Amat + (size_t)(m0 + row) * KDIM + k0 + scol, aDst + c * 512);
      gload16(BT   + (size_t)(n0 + row) * KDIM + k0 + scol, bDst + c * 512);
    }
  };

  // LDS byte bases (generic->uintptr truncation keeps LDS offset; same
  // mechanism gload16 has used correctly since R2).
  const uint32_t aOff0 = (uint32_t)(uintptr_t)As0;
  const uint32_t aOff1 = (uint32_t)(uintptr_t)As1;
  const uint32_t bOff0 = (uint32_t)(uintptr_t)Bs0;
  const uint32_t bOff1 = (uint32_t)(uintptr_t)Bs1;

  f32x4 acc[4][4] = {};
  auto compute = [&](uint32_t aBase, uint32_t bBase) {
    bf16x8 af[4], bq[4];
    #pragma unroll
    for (int m = 0; m < 4; ++m) {
      const int r = wm + m * 16 + lr;
      af[m] = ds_read_b128(aBase + r * 64 + ((kg4 ^ (r & 3)) << 4));
    }
    #pragma unroll
    for (int n = 0; n < 4; ++n) {
      const int r = wn + n * 16 + lr;
      bq[n] = ds_read_b128(bBase + r * 64 + ((kg4 ^ (r & 3)) << 4));
    }
    asm volatile("s_waitcnt lgkmcnt(0)" ::: "memory");
    __builtin_amdgcn_sched_barrier(0);                 // rule #18
    __builtin_amdgcn_s_setprio(1);
    #pragma unroll
    for (int m = 0; m < 4; ++m)
      #pragma unroll
      for (int n = 0; n < 4; ++n)
        acc[m][n] = __builtin_amdgcn_mfma_f32_16x16x32_bf16(af[m], bq[n], acc[m][n], 0, 0, 0);
    __builtin_amdgcn_s_setprio(0);
  };

  stage(As0, Bs0, 0);                                  // 4 loads in flight
  constexpr int NT = KDIM / 32;
  #pragma unroll
  for (int t = 0; t < NT; ++t) {
    if (t + 1 < NT) {
      stage(((t + 1) & 1) ? As1 : As0, ((t + 1) & 1) ? Bs1 : Bs0, (t + 1) * 32);
      asm volatile("s_waitcnt vmcnt(4)" ::: "memory"); // t done; t+1 in flight
    } else {
      asm volatile("s_waitcnt vmcnt(0)" ::: "memory");
    }
    __builtin_amdgcn_sched_barrier(0);
    __builtin_amdgcn_s_barrier();                      // buf t complete (all waves)
    compute((t & 1) ? aOff1 : aOff0, (t & 1) ? bOff1 : bOff0);
    __builtin_amdgcn_s_barrier();                      // protect buf before overwrite
  }
  __builtin_amdgcn_sched_barrier(0);
  // all compute done -> LDS reusable as scratch.

  if constexpr (EPI == 0 || EPI == 1) {
    short* scr = &sm[wave * 4096];                     // 64x64 bf16, rows 128B
    const int colbase = n0 + wn;
    const float* bp;
    int cb;
    if constexpr (EPI == 0) {
      const int which = colbase >> 8;
      bp = which == 0 ? bias0 : (which == 1 ? bias1 : bias2);
      cb = colbase & 255;
    } else { bp = bias0; cb = colbase; }
    // scratch 16B-slot XOR swizzle: slot s (0..7) -> s ^ ((row&3)<<1); spreads
    // the 4 kg4 row-groups across distinct 32B bank regions (write side) and
    // permutes within rows only (read side stays one b128 per lane).
    #pragma unroll
    for (int m = 0; m < 4; ++m)
      #pragma unroll
      for (int n = 0; n < 4; ++n)
        #pragma unroll
        for (int r = 0; r < 4; ++r) {
          const int lrow = m * 16 + kg4 * 4 + r;
          const int lcol = n * 16 + lr;
          float v = acc[m][n][r] + bp[cb + lcol];
          if constexpr (EPI == 1) v = gelu_fast(v);
          const int sc = lcol ^ ((lrow & 3) << 4);
          scr[lrow * 64 + sc] = f2bf(v);
        }
    const int rl = lane >> 3, cl = (lane & 7) * 8;     // 8 lanes/row, 16B/lane
    bf16_t* const obase = (EPI == 0)
        ? Obf + (size_t)(colbase >> 8) * kRows * kC
        : Obf;
    const int ld = (EPI == 0) ? kC : kFF;
    #pragma unroll
    for (int p = 0; p < 8; ++p) {
      const int lrow = p * 8 + rl;
      const int sc = cl ^ ((lrow & 3) << 4);
      bf16x8 v = *reinterpret_cast<const bf16x8*>(&scr[lrow * 64 + sc]);
      *reinterpret_cast<bf16x8*>(
          obase + (size_t)(m0 + wm + lrow) * ld + cb + cl) = v;
    }
  } else {
    float* scrf = reinterpret_cast<float*>(&sm[wave * 4096]);  // 64x32 f32
    #pragma unroll
    for (int h = 0; h < 2; ++h) {
      #pragma unroll
      for (int m = 0; m < 4; ++m)
        #pragma unroll
        for (int nn = 0; nn < 2; ++nn) {
          const int n = h * 2 + nn;
          #pragma unroll
          for (int r = 0; r < 4; ++r) {
            const int lrow = m * 16 + kg4 * 4 + r;
            const int lcol = nn * 16 + lr;
            scrf[lrow * 32 + (lcol ^ ((lrow & 3) << 3))] =
                acc[m][n][r] + bias0[n0 + wn + n * 16 + lr];
          }
        }
      const int rl = lane >> 3, cl = (lane & 7) * 4;   // 8 lanes/row, 16B/lane
      #pragma unroll
      for (int p = 0; p < 8; ++p) {
        const int lrow = p * 8 + rl;
        const int row = m0 + wm + lrow;
        const int col = n0 + wn + h * 32 + cl;
        float4 v = *reinterpret_cast<const float4*>(
            &scrf[lrow * 32 + (cl ^ ((lrow & 3) << 3))]);
        const float4 a4 = *reinterpret_cast<const float4*>(
            &Ares[(size_t)row * kC + col]);
        v.x += a4.x; v.y += a4.y; v.z += a4.z; v.w += a4.w;
        int b, g1, g2; row_coords(row, b, g1, g2);
        *reinterpret_cast<float4*>(
            &Out[(((size_t)b * kGRID + g1) * kGRID + g2) * kC + col]) = v;
      }
      if (h == 0) __builtin_amdgcn_s_barrier();        // wave-local reuse; keep waves in step
    }
  }
}

// ---------------- MFMA attention (R11, unchanged)
constexpr int kKsPad = 40;
constexpr int kVtPad = 200;
constexpr int kPlPad = 200;
__global__ __launch_bounds__(256) void k_attn(
    const bf16_t* __restrict__ Q, const bf16_t* __restrict__ K,
    const bf16_t* __restrict__ V, const float* __restrict__ pos,
    bf16_t* __restrict__ SA) {
  __shared__ short Ks[kP * kKsPad];
  __shared__ short Vt[kDh * kVtPad];
  __shared__ short Pl[4 * 16 * kPlPad];
  const int bw = blockIdx.x >> 3, h = blockIdx.x & 7;
  const int rowbase = bw * kP, colbase = h * kDh;
  const int tid = threadIdx.x, wave = tid >> 6, lane = tid & 63;
  const int lr = lane & 15, kg = lane >> 4;
  const int wq0 = wave * 48;
  const float* pb = pos + (size_t)h * kP * kP;

  #pragma unroll
  for (int i = 0; i < 3; ++i) {
    const int c = tid + i * 256;
    const int row = c >> 2, dch = (c & 3) * 8;
    const size_t gbase = (size_t)(rowbase + row) * kC + colbase + dch;
    bf16x8 kv = *reinterpret_cast<const bf16x8*>(K + gbase);
    *reinterpret_cast<bf16x8*>(&Ks[row * kKsPad + dch]) = kv;
    bf16x8 vv = *reinterpret_cast<const bf16x8*>(V + gbase);
    #pragma unroll
    for (int e = 0; e < 8; ++e) Vt[(dch + e) * kVtPad + row] = vv[e];
  }
  __syncthreads();

  for (int m = 0; m < 3; ++m) {
    const int rbase = wq0 + m * 16;
    bf16x8 aq = *reinterpret_cast<const bf16x8*>(
        Q + (size_t)(rowbase + rbase + lr) * kC + colbase + kg * 8);
    f32x4 s[12];
    #pragma unroll
    for (int n = 0; n < 12; ++n) {
      bf16x8 bk = *reinterpret_cast<const bf16x8*>(&Ks[(n * 16 + lr) * kKsPad + kg * 8]);
      s[n] = __builtin_amdgcn_mfma_f32_16x16x32_bf16(aq, bk, (f32x4){0.f, 0.f, 0.f, 0.f}, 0, 0, 0);
    }
    float mx[4] = {-1e30f, -1e30f, -1e30f, -1e30f};
    #pragma unroll
    for (int n = 0; n < 12; ++n) {
      #pragma unroll
      for (int r = 0; r < 4; ++r) {
        const float lg = fmaf(s[n][r], kScale,
                              pb[(size_t)(rbase + kg * 4 + r) * kP + n * 16 + lr]);
        s[n][r] = lg;
        mx[r] = fmaxf(mx[r], lg);
      }
    }
    #pragma unroll
    for (int r = 0; r < 4; ++r)
      #pragma unroll
      for (int off = 8; off; off >>= 1) mx[r] = fmaxf(mx[r], __shfl_xor(mx[r], off));
    float sm4[4] = {0.f, 0.f, 0.f, 0.f};
    #pragma unroll
    for (int n = 0; n < 12; ++n)
      #pragma unroll
      for (int r = 0; r < 4; ++r) {
        const float e = __expf(s[n][r] - mx[r]);
        s[n][r] = e;
        sm4[r] += e;
      }
    #pragma unroll
    for (int r = 0; r < 4; ++r) {
      #pragma unroll
      for (int off = 8; off; off >>= 1) sm4[r] += __shfl_xor(sm4[r], off);
      sm4[r] = 1.f / sm4[r];
    }
    #pragma unroll
    for (int n = 0; n < 12; ++n)
      #pragma unroll
      for (int r = 0; r < 4; ++r)
        Pl[(wave * 16 + kg * 4 + r) * kPlPad + n * 16 + lr] = f2bf(s[n][r] * sm4[r]);
    f32x4 o0 = {0.f, 0.f, 0.f, 0.f}, o1 = {0.f, 0.f, 0.f, 0.f};
    #pragma unroll
    for (int kk = 0; kk < 6; ++kk) {
      bf16x8 ap = *reinterpret_cast<const bf16x8*>(&Pl[(wave * 16 + lr) * kPlPad + kk * 32 + kg * 8]);
      bf16x8 b0 = *reinterpret_cast<const bf16x8*>(&Vt[lr * kVtPad + kk * 32 + kg * 8]);
      bf16x8 b1 = *reinterpret_cast<const bf16x8*>(&Vt[(16 + lr) * kVtPad + kk * 32 + kg * 8]);
      o0 = __builtin_amdgcn_mfma_f32_16x16x32_bf16(ap, b0, o0, 0, 0, 0);
      o1 = __builtin_amdgcn_mfma_f32_16x16x32_bf16(ap, b1, o1, 0, 0, 0);
    }
    short* scr2 = &Pl[wave * 16 * kPlPad];
    #pragma unroll
    for (int r = 0; r < 4; ++r) {
      scr2[(kg * 4 + r) * 32 + lr]      = f2bf(o0[r]);
      scr2[(kg * 4 + r) * 32 + 16 + lr] = f2bf(o1[r]);
    }
    {
      const int rrow = lane >> 2, c0 = (lane & 3) * 8;
      bf16x8 v = *reinterpret_cast<const bf16x8*>(&scr2[rrow * 32 + c0]);
      *reinterpret_cast<bf16x8*>(
          SA + (size_t)(rowbase + rbase + rrow) * kC + colbase + c0) = v;
    }
  }
}

extern "C" void kernel_launch(void* const* d_in, const int* in_sizes, int n_in,
                              void* d_out, int out_size, void* d_ws, size_t ws_size,
                              hipStream_t stream) {
  const float* emb  = (const float*)d_in[0];
  const float* ln1g = (const float*)d_in[1];
  const float* ln1b = (const float*)d_in[2];
  const float* wq   = (const float*)d_in[3];
  const float* bq   = (const float*)d_in[4];
  const float* wk   = (const float*)d_in[5];
  const float* bk   = (const float*)d_in[6];
  const float* wv   = (const float*)d_in[7];
  const float* bv   = (const float*)d_in[8];
  const float* pos  = (const float*)d_in[9];
  const float* ln2g = (const float*)d_in[10];
  const float* ln2b = (const float*)d_in[11];
  const float* w1   = (const float*)d_in[12];
  const float* b1   = (const float*)d_in[13];
  const float* w2   = (const float*)d_in[14];
  const float* b2   = (const float*)d_in[15];

  char* ws = (char*)d_ws;
  const size_t nYb = (size_t)kRows * kC * 2;               // 18,874,368 B
  bf16_t* Y    = (bf16_t*)(ws);                            // [0, 18.9M)
  bf16_t* Qb   = (bf16_t*)(ws + nYb);                      // Q,K,V consecutive
  bf16_t* SAb  = (bf16_t*)(ws + nYb * 4);                  // [75.5M, 94.4M)
  float*  Abuf = (float*) (ws + nYb * 5);                  // [94.4M, 132.1M)
  bf16_t* H    = (bf16_t*)(ws + nYb * 5 + (size_t)kRows * kC * 4);  // [132.1M, 151M)
  bf16_t* G    = (bf16_t*)(ws);                            // alias dead Y/Q/K/V
  bf16_t* W    = (bf16_t*)(ws + nYb * 5 + (size_t)kRows * kC * 4 + nYb);
  bf16_t* WqkvT = W;
  bf16_t* W1T   = W + 768 * 256;
  bf16_t* W2T   = W1T + 1024 * 256;

  k_wconv<<<2816, 256, 0, stream>>>(wq, wk, wv, w1, w2, W);
  k_ln1<<<kRows / 8, 256, 0, stream>>>(emb, ln1g, ln1b, Y);
  k_gemm6<256, 0, 6><<<(kRows / 128) * 6, 256, 0, stream>>>(
      Y, WqkvT, bq, bk, bv, Qb, nullptr, nullptr);
  k_attn<<<kB * kNW * kNH, 256, 0, stream>>>(
      Qb, Qb + (size_t)kRows * kC, Qb + 2 * (size_t)kRows * kC, pos, SAb);
  k_ln2<<<kRows / 8, 256, 0, stream>>>(emb, SAb, ln2g, ln2b, Abuf, H);
  k_gemm6<256, 1, 8><<<(kRows / 128) * 8, 256, 0, stream>>>(
      H, W1T, b1, nullptr, nullptr, G, nullptr, nullptr);
  k_gemm6<1024, 2, 2><<<(kRows / 128) * 2, 256, 0, stream>>>(
      G, W2T, b2, nullptr, nullptr, nullptr, Abuf, (float*)d_out);
}